// Round 5
// baseline (34.000 us; speedup 1.0000x reference)
//
#include <hip/hip_runtime.h>
#include <cmath>

// RTMDet decode, fused, class-split-across-threads + conflict-free LDS merge.
// Per spatial position: conf = sigmoid(max_c logit), class = argmax_c logit (first occurrence),
// box = clip([gx-l, gy-t, gx+r, gy+d], 0, 639), gx = w*step, gy = h*step.
// Output layout (flat float32 in d_out): boxes [64,8400,4] | scores [64,8400] | classes [64,8400].
//
// Grid: 2100 blocks x 256 threads (level boundaries on block boundaries):
//   [0,1600)    -> level 0 (80x80, step 8)
//   [1600,2000) -> level 1 (40x40, step 16)
//   [2000,2100) -> level 2 (20x20, step 32)
//
// Each block owns 128 pairs (256 positions). Threads 0-127 scan classes [0,40) for pairs
// 0-127 (float2 loads), threads 128-255 scan classes [40,80) for the same pairs. Partials
// meet in LDS (scalar SoA arrays -> bank = tid&31, 2 lanes/bank = free on wave64); after one
// barrier the low half merges (lower class index wins ties) and stores scores/classes.
// R3 lesson applied: no __shfl (was lowered through LDS with 1.3M bank conflicts).
// Box path: 1 position/thread, 4 coalesced scalar loads, 1 coalesced float4 store.

constexpr int B_   = 64;
constexpr int NC   = 80;
constexpr int NTOT = 8400;   // 6400 + 1600 + 400

__device__ __forceinline__ float sigmoidf_(float x) { return 1.0f / (1.0f + __expf(-x)); }

template<int HW, int W, int STEP, int NOFF>
__device__ __forceinline__ void decode_level(
    const float* __restrict__ cls, const float* __restrict__ box,
    float* __restrict__ oboxes, float* __restrict__ oscores, float* __restrict__ oclasses,
    int lbid, int tid,
    float* __restrict__ sm0, float* __restrict__ sm1,
    int*   __restrict__ sc0, int*   __restrict__ sc1)
{
    constexpr int PPI = HW / 2;                 // pairs per image

    int half = tid >> 7;                        // class half: 0 -> [0,40), 1 -> [40,80)
    int lp   = tid & 127;                       // local pair in block
    int pair = lbid * 128 + lp;                 // level-local pair, in [0, 64*PPI)
    int b    = pair / PPI;                      // compile-time PPI -> magic mul
    int p    = (pair - b * PPI) << 1;           // first of 2 consecutive positions

    // ---------- partial class max/argmax: 40 classes per thread, float2 loads ----------
    const float* cbase = cls + (size_t)b * NC * HW + (size_t)(half * 40) * HW + p;
    float m[2]  = {-3.4e38f, -3.4e38f};
    int   ci[2] = {0, 0};
    #pragma unroll 8
    for (int c = 0; c < 40; ++c) {
        float2 v = *reinterpret_cast<const float2*>(cbase + (size_t)c * HW);
        if (v.x > m[0]) { m[0] = v.x; ci[0] = c; }   // strict > : first occurrence
        if (v.y > m[1]) { m[1] = v.y; ci[1] = c; }
    }

    sm0[tid] = m[0];  sm1[tid] = m[1];          // scalar SoA -> conflict-free
    sc0[tid] = ci[0]; sc1[tid] = ci[1];
    __syncthreads();

    if (tid < 128) {                            // merge: low half owns the pair
        int pr = tid + 128;
        float om0 = sm0[pr], om1 = sm1[pr];
        int   oc0 = sc0[pr] + 40, oc1 = sc1[pr] + 40;
        // my ci already global (half==0). Ties: lower class index wins (mine, since +40 > mine).
        if (om0 > m[0]) { m[0] = om0; ci[0] = oc0; }
        if (om1 > m[1]) { m[1] = om1; ci[1] = oc1; }

        size_t obase = (size_t)b * NTOT + NOFF + p;
        *reinterpret_cast<float2*>(oscores  + obase) =
            make_float2(sigmoidf_(m[0]), sigmoidf_(m[1]));
        *reinterpret_cast<float2*>(oclasses + obase) =
            make_float2((float)ci[0], (float)ci[1]);
    }

    // ---------- boxes: 1 lane-contiguous position per thread ----------
    {
        int P  = lbid * 256 + tid;              // level-local element pos in [0, 64*HW)
        int bb = P / HW;                        // compile-time HW -> magic mul
        int pp = P - bb * HW;
        int hh = pp / W;                        // compile-time W -> magic mul
        int ww = pp - hh * W;

        const float* bbase = box + (size_t)bb * 4 * HW + pp;
        float l  = bbase[0];                    // lanes at consecutive pp -> coalesced
        float tt = bbase[HW];
        float r  = bbase[2 * HW];
        float dd = bbase[3 * HW];

        float gx = (float)(ww * STEP);
        float gy = (float)(hh * STEP);
        float4 o;
        o.x = fminf(fmaxf(gx - l,  0.0f), 639.0f);
        o.y = fminf(fmaxf(gy - tt, 0.0f), 639.0f);
        o.z = fminf(fmaxf(gx + r,  0.0f), 639.0f);
        o.w = fminf(fmaxf(gy + dd, 0.0f), 639.0f);

        size_t ob = (size_t)bb * NTOT + NOFF + pp;
        *reinterpret_cast<float4*>(oboxes + ob * 4) = o;    // lanes contiguous -> coalesced
    }
}

__global__ __launch_bounds__(256) void rtmdet_decode_fused(
    const float* __restrict__ cls0, const float* __restrict__ box0,
    const float* __restrict__ cls1, const float* __restrict__ box1,
    const float* __restrict__ cls2, const float* __restrict__ box2,
    float* __restrict__ oboxes, float* __restrict__ oscores, float* __restrict__ oclasses)
{
    __shared__ float sm0[256], sm1[256];
    __shared__ int   sc0[256], sc1[256];

    int bid = blockIdx.x;
    int tid = threadIdx.x;
    if (bid < 1600) {
        decode_level<6400, 80,  8,    0>(cls0, box0, oboxes, oscores, oclasses, bid,
                                         tid, sm0, sm1, sc0, sc1);
    } else if (bid < 2000) {
        decode_level<1600, 40, 16, 6400>(cls1, box1, oboxes, oscores, oclasses, bid - 1600,
                                         tid, sm0, sm1, sc0, sc1);
    } else {
        decode_level< 400, 20, 32, 8000>(cls2, box2, oboxes, oscores, oclasses, bid - 2000,
                                         tid, sm0, sm1, sc0, sc1);
    }
}

extern "C" void kernel_launch(void* const* d_in, const int* in_sizes, int n_in,
                              void* d_out, int out_size, void* d_ws, size_t ws_size,
                              hipStream_t stream) {
    const float* cls0 = (const float*)d_in[0];
    const float* box0 = (const float*)d_in[1];
    const float* cls1 = (const float*)d_in[2];
    const float* box1 = (const float*)d_in[3];
    const float* cls2 = (const float*)d_in[4];
    const float* box2 = (const float*)d_in[5];

    float* oboxes   = (float*)d_out;
    float* oscores  = oboxes  + (size_t)B_ * NTOT * 4;
    float* oclasses = oscores + (size_t)B_ * NTOT;

    rtmdet_decode_fused<<<2100, 256, 0, stream>>>(cls0, box0, cls1, box1, cls2, box2,
                                                  oboxes, oscores, oclasses);
}

// Round 6
// 33.710 us; speedup vs baseline: 1.0086x; 1.0086x over previous
//
#include <hip/hip_runtime.h>
#include <cmath>

// RTMDet decode, fused: float4 cls loads + 2-way class split + conflict-free LDS merge.
// Per spatial position: conf = sigmoid(max_c logit), class = argmax_c logit (first occurrence),
// box = clip([gx-l, gy-t, gx+r, gy+d], 0, 639), gx = w*step, gy = h*step.
// Output layout (flat float32 in d_out): boxes [64,8400,4] | scores [64,8400] | classes [64,8400].
//
// Theory: steady-state inputs are L3-resident (FETCH~0, writes-only to HBM) and occupancy is
// no longer the lever (R4 16w/CU == R5 32w/CU). Limit = VMEM instruction issue (64 addresses
// per wave64 instr at fixed lane rate). So: maximize bytes/instr (float4 = 1024 B) AND keep
// ~16 waves/CU. Each block: 128 quads (512 positions) x 2 class-halves; thread scans 40
// classes via float4; partials meet in LDS scalar SoA (bank = tid&31, 2 lanes/bank = free);
// ci[4] packed into one int (values 0..39 fit 8 bits). Low half merges (lower class index
// wins ties) and does the float4 score/class stores.
//
// Grid: 1050 blocks x 256 threads, level boundaries on block boundaries:
//   [0,800) -> level 0 (80x80, s8) | [800,1000) -> level 1 (40x40, s16) | [1000,1050) -> lvl 2.

constexpr int B_   = 64;
constexpr int NC   = 80;
constexpr int NTOT = 8400;   // 6400 + 1600 + 400

__device__ __forceinline__ float sigmoidf_(float x) { return 1.0f / (1.0f + __expf(-x)); }

template<int HW, int W, int STEP, int NOFF>
__device__ __forceinline__ void decode_level(
    const float* __restrict__ cls, const float* __restrict__ box,
    float* __restrict__ oboxes, float* __restrict__ oscores, float* __restrict__ oclasses,
    int lbid, int tid,
    float (* __restrict__ sm)[256], int* __restrict__ spk)
{
    constexpr int QPI = HW / 4;                 // quads per image
    constexpr int PPI = HW / 2;                 // pairs per image

    int half = tid >> 7;                        // class half: 0 -> [0,40), 1 -> [40,80)
    int lp   = tid & 127;                       // local quad in block
    int quad = lbid * 128 + lp;                 // level-local quad, in [0, 64*QPI)
    int b    = quad / QPI;                      // compile-time QPI -> magic mul
    int p    = (quad - b * QPI) << 2;           // first of 4 consecutive positions

    // ---------- partial class max/argmax: 40 classes per thread, float4 loads ----------
    const float* cbase = cls + (size_t)b * NC * HW + (size_t)(half * 40) * HW + p;
    float m[4]  = {-3.4e38f, -3.4e38f, -3.4e38f, -3.4e38f};
    int   ci[4] = {0, 0, 0, 0};
    #pragma unroll 8
    for (int c = 0; c < 40; ++c) {
        float4 v = *reinterpret_cast<const float4*>(cbase + (size_t)c * HW);
        float vv[4] = {v.x, v.y, v.z, v.w};
        #pragma unroll
        for (int j = 0; j < 4; ++j) {
            if (vv[j] > m[j]) { m[j] = vv[j]; ci[j] = c; }   // strict > : first occurrence
        }
    }

    #pragma unroll
    for (int j = 0; j < 4; ++j) sm[j][tid] = m[j];
    spk[tid] = ci[0] | (ci[1] << 8) | (ci[2] << 16) | (ci[3] << 24);
    __syncthreads();

    if (tid < 128) {                            // merge: low half owns the quad
        int pr  = tid + 128;
        int opk = spk[pr];
        float4 osc, ocl;
        float* oscp = &osc.x;
        float* oclp = &ocl.x;
        #pragma unroll
        for (int j = 0; j < 4; ++j) {
            float om = sm[j][pr];
            int   oc = ((opk >> (8 * j)) & 0xFF) + 40;
            float mm = m[j];
            int   cc = ci[j];                   // already global (half 0)
            if (om > mm) { mm = om; cc = oc; }  // ties -> lower index = mine
            oscp[j] = sigmoidf_(mm);
            oclp[j] = (float)cc;
        }
        size_t obase = (size_t)b * NTOT + NOFF + p;
        *reinterpret_cast<float4*>(oscores  + obase) = osc;   // lanes contiguous -> coalesced
        *reinterpret_cast<float4*>(oclasses + obase) = ocl;
    }

    // ---------- boxes: 1 pair (2 consecutive positions) per thread ----------
    {
        int pair = lbid * 256 + tid;            // level-local pair, in [0, 64*PPI)
        int bb   = pair / PPI;                  // compile-time PPI -> magic mul
        int pp   = (pair - bb * PPI) << 1;
        int hh   = pp / W;                      // compile-time W -> magic mul
        int ww   = pp - hh * W;

        const float* bbase = box + (size_t)bb * 4 * HW + pp;
        float2 bl = *reinterpret_cast<const float2*>(bbase);
        float2 bt = *reinterpret_cast<const float2*>(bbase + HW);
        float2 br = *reinterpret_cast<const float2*>(bbase + 2 * HW);
        float2 bd = *reinterpret_cast<const float2*>(bbase + 3 * HW);

        float gy = (float)(hh * STEP);
        size_t ob = (size_t)bb * NTOT + NOFF + pp;
        #pragma unroll
        for (int j = 0; j < 2; ++j) {
            float gx = (float)((ww + j) * STEP);
            float l  = j ? bl.y : bl.x;
            float tt = j ? bt.y : bt.x;
            float r  = j ? br.y : br.x;
            float dd = j ? bd.y : bd.x;
            float4 o;
            o.x = fminf(fmaxf(gx - l,  0.0f), 639.0f);
            o.y = fminf(fmaxf(gy - tt, 0.0f), 639.0f);
            o.z = fminf(fmaxf(gx + r,  0.0f), 639.0f);
            o.w = fminf(fmaxf(gy + dd, 0.0f), 639.0f);
            *reinterpret_cast<float4*>(oboxes + (ob + j) * 4) = o;  // coalesced float4
        }
    }
}

__global__ __launch_bounds__(256) void rtmdet_decode_fused(
    const float* __restrict__ cls0, const float* __restrict__ box0,
    const float* __restrict__ cls1, const float* __restrict__ box1,
    const float* __restrict__ cls2, const float* __restrict__ box2,
    float* __restrict__ oboxes, float* __restrict__ oscores, float* __restrict__ oclasses)
{
    __shared__ float sm[4][256];
    __shared__ int   spk[256];

    int bid = blockIdx.x;
    int tid = threadIdx.x;
    if (bid < 800) {
        decode_level<6400, 80,  8,    0>(cls0, box0, oboxes, oscores, oclasses, bid,
                                         tid, sm, spk);
    } else if (bid < 1000) {
        decode_level<1600, 40, 16, 6400>(cls1, box1, oboxes, oscores, oclasses, bid - 800,
                                         tid, sm, spk);
    } else {
        decode_level< 400, 20, 32, 8000>(cls2, box2, oboxes, oscores, oclasses, bid - 1000,
                                         tid, sm, spk);
    }
}

extern "C" void kernel_launch(void* const* d_in, const int* in_sizes, int n_in,
                              void* d_out, int out_size, void* d_ws, size_t ws_size,
                              hipStream_t stream) {
    const float* cls0 = (const float*)d_in[0];
    const float* box0 = (const float*)d_in[1];
    const float* cls1 = (const float*)d_in[2];
    const float* box1 = (const float*)d_in[3];
    const float* cls2 = (const float*)d_in[4];
    const float* box2 = (const float*)d_in[5];

    float* oboxes   = (float*)d_out;
    float* oscores  = oboxes  + (size_t)B_ * NTOT * 4;
    float* oclasses = oscores + (size_t)B_ * NTOT;

    rtmdet_decode_fused<<<1050, 256, 0, stream>>>(cls0, box0, cls1, box1, cls2, box2,
                                                  oboxes, oscores, oclasses);
}

// Round 7
// 33.552 us; speedup vs baseline: 1.0133x; 1.0047x over previous
//
#include <hip/hip_runtime.h>
#include <cmath>

// RTMDet decode, fused: float4 cls loads + 2-way class split + LDS merge + 8-deep
// register double-buffer on the class scan (MLP fix).
// Per spatial position: conf = sigmoid(max_c logit), class = argmax_c logit (first occurrence),
// box = clip([gx-l, gy-t, gx+r, gy+d], 0, 639), gx = w*step, gy = h*step.
// Output layout (flat float32 in d_out): boxes [64,8400,4] | scores [64,8400] | classes [64,8400].
//
// R6 post-mortem: occupancy (R4/R5) and VMEM-instr count (R6) both null; VGPR_Count=32 means
// ~2 loads in flight/wave -> latency-bound at ~5.7 TB/s aggregate (L3-resident streaming).
// Here: 40 classes = 5 batches x 8 float4 loads, prefetch batch i+1 while reducing batch i
// (8 KB in flight per wave). __launch_bounds__(256,4) caps VGPR at 128 -> 16 waves/CU.
//
// Grid: 1050 blocks x 256 threads, level boundaries on block boundaries:
//   [0,800) -> level 0 (80x80, s8) | [800,1000) -> level 1 (40x40, s16) | [1000,1050) -> lvl 2.

constexpr int B_   = 64;
constexpr int NC   = 80;
constexpr int NTOT = 8400;   // 6400 + 1600 + 400

__device__ __forceinline__ float sigmoidf_(float x) { return 1.0f / (1.0f + __expf(-x)); }

template<int HW, int W, int STEP, int NOFF>
__device__ __forceinline__ void decode_level(
    const float* __restrict__ cls, const float* __restrict__ box,
    float* __restrict__ oboxes, float* __restrict__ oscores, float* __restrict__ oclasses,
    int lbid, int tid,
    float (* __restrict__ sm)[256], int* __restrict__ spk)
{
    constexpr int QPI = HW / 4;                 // quads per image
    constexpr int PPI = HW / 2;                 // pairs per image

    int half = tid >> 7;                        // class half: 0 -> [0,40), 1 -> [40,80)
    int lp   = tid & 127;                       // local quad in block
    int quad = lbid * 128 + lp;                 // level-local quad, in [0, 64*QPI)
    int b    = quad / QPI;                      // compile-time QPI -> magic mul
    int p    = (quad - b * QPI) << 2;           // first of 4 consecutive positions

    // ---------- partial class max/argmax: 40 classes, 5 batches x 8 float4, prefetched ----------
    const float* cbase = cls + (size_t)b * NC * HW + (size_t)(half * 40) * HW + p;
    float m[4]  = {-3.4e38f, -3.4e38f, -3.4e38f, -3.4e38f};
    int   ci[4] = {0, 0, 0, 0};

    float4 buf[8], nxt[8];
    #pragma unroll
    for (int i = 0; i < 8; ++i)
        buf[i] = *reinterpret_cast<const float4*>(cbase + (size_t)i * HW);

    #pragma unroll
    for (int batch = 0; batch < 5; ++batch) {
        if (batch < 4) {                        // compile-time after full unroll
            #pragma unroll
            for (int i = 0; i < 8; ++i)
                nxt[i] = *reinterpret_cast<const float4*>(cbase + (size_t)((batch + 1) * 8 + i) * HW);
        }
        #pragma unroll
        for (int i = 0; i < 8; ++i) {
            int c = batch * 8 + i;
            float vv[4] = {buf[i].x, buf[i].y, buf[i].z, buf[i].w};
            #pragma unroll
            for (int j = 0; j < 4; ++j) {
                if (vv[j] > m[j]) { m[j] = vv[j]; ci[j] = c; }   // strict > : first occurrence
            }
        }
        #pragma unroll
        for (int i = 0; i < 8; ++i) buf[i] = nxt[i];
    }

    #pragma unroll
    for (int j = 0; j < 4; ++j) sm[j][tid] = m[j];
    spk[tid] = ci[0] | (ci[1] << 8) | (ci[2] << 16) | (ci[3] << 24);
    __syncthreads();

    if (tid < 128) {                            // merge: low half owns the quad
        int pr  = tid + 128;
        int opk = spk[pr];
        float4 osc, ocl;
        float* oscp = &osc.x;
        float* oclp = &ocl.x;
        #pragma unroll
        for (int j = 0; j < 4; ++j) {
            float om = sm[j][pr];
            int   oc = ((opk >> (8 * j)) & 0xFF) + 40;
            float mm = m[j];
            int   cc = ci[j];                   // already global (half 0)
            if (om > mm) { mm = om; cc = oc; }  // ties -> lower index = mine
            oscp[j] = sigmoidf_(mm);
            oclp[j] = (float)cc;
        }
        size_t obase = (size_t)b * NTOT + NOFF + p;
        *reinterpret_cast<float4*>(oscores  + obase) = osc;   // lanes contiguous -> coalesced
        *reinterpret_cast<float4*>(oclasses + obase) = ocl;
    }

    // ---------- boxes: 1 pair (2 consecutive positions) per thread ----------
    {
        int pair = lbid * 256 + tid;            // level-local pair, in [0, 64*PPI)
        int bb   = pair / PPI;                  // compile-time PPI -> magic mul
        int pp   = (pair - bb * PPI) << 1;
        int hh   = pp / W;                      // compile-time W -> magic mul
        int ww   = pp - hh * W;

        const float* bbase = box + (size_t)bb * 4 * HW + pp;
        float2 bl = *reinterpret_cast<const float2*>(bbase);
        float2 bt = *reinterpret_cast<const float2*>(bbase + HW);
        float2 br = *reinterpret_cast<const float2*>(bbase + 2 * HW);
        float2 bd = *reinterpret_cast<const float2*>(bbase + 3 * HW);

        float gy = (float)(hh * STEP);
        size_t ob = (size_t)bb * NTOT + NOFF + pp;
        #pragma unroll
        for (int j = 0; j < 2; ++j) {
            float gx = (float)((ww + j) * STEP);
            float l  = j ? bl.y : bl.x;
            float tt = j ? bt.y : bt.x;
            float r  = j ? br.y : br.x;
            float dd = j ? bd.y : bd.x;
            float4 o;
            o.x = fminf(fmaxf(gx - l,  0.0f), 639.0f);
            o.y = fminf(fmaxf(gy - tt, 0.0f), 639.0f);
            o.z = fminf(fmaxf(gx + r,  0.0f), 639.0f);
            o.w = fminf(fmaxf(gy + dd, 0.0f), 639.0f);
            *reinterpret_cast<float4*>(oboxes + (ob + j) * 4) = o;  // coalesced float4
        }
    }
}

__global__ __launch_bounds__(256, 4) void rtmdet_decode_fused(
    const float* __restrict__ cls0, const float* __restrict__ box0,
    const float* __restrict__ cls1, const float* __restrict__ box1,
    const float* __restrict__ cls2, const float* __restrict__ box2,
    float* __restrict__ oboxes, float* __restrict__ oscores, float* __restrict__ oclasses)
{
    __shared__ float sm[4][256];
    __shared__ int   spk[256];

    int bid = blockIdx.x;
    int tid = threadIdx.x;
    if (bid < 800) {
        decode_level<6400, 80,  8,    0>(cls0, box0, oboxes, oscores, oclasses, bid,
                                         tid, sm, spk);
    } else if (bid < 1000) {
        decode_level<1600, 40, 16, 6400>(cls1, box1, oboxes, oscores, oclasses, bid - 800,
                                         tid, sm, spk);
    } else {
        decode_level< 400, 20, 32, 8000>(cls2, box2, oboxes, oscores, oclasses, bid - 1000,
                                         tid, sm, spk);
    }
}

extern "C" void kernel_launch(void* const* d_in, const int* in_sizes, int n_in,
                              void* d_out, int out_size, void* d_ws, size_t ws_size,
                              hipStream_t stream) {
    const float* cls0 = (const float*)d_in[0];
    const float* box0 = (const float*)d_in[1];
    const float* cls1 = (const float*)d_in[2];
    const float* box1 = (const float*)d_in[3];
    const float* cls2 = (const float*)d_in[4];
    const float* box2 = (const float*)d_in[5];

    float* oboxes   = (float*)d_out;
    float* oscores  = oboxes  + (size_t)B_ * NTOT * 4;
    float* oclasses = oscores + (size_t)B_ * NTOT;

    rtmdet_decode_fused<<<1050, 256, 0, stream>>>(cls0, box0, cls1, box1, cls2, box2,
                                                  oboxes, oscores, oclasses);
}